// Round 8
// baseline (213.744 us; speedup 1.0000x reference)
//
#include <hip/hip_runtime.h>
#include <math.h>

#define NWIN 4096    // (64/4)^3 windows

typedef unsigned short u16;
typedef unsigned int u32;
typedef __bf16 bf16;
typedef __attribute__((ext_vector_type(8))) __bf16 bf16x8;
typedef __attribute__((ext_vector_type(4))) float f32x4;

__device__ __forceinline__ u16 f2b(float f){
  return __builtin_bit_cast(u16, (bf16)f);
}
__device__ __forceinline__ u32 pack2(float lo, float hi){
  return ((u32)f2b(hi) << 16) | (u32)f2b(lo);
}
__device__ __forceinline__ float grp16_sum(float v){
  v += __shfl_xor(v, 1); v += __shfl_xor(v, 2);
  v += __shfl_xor(v, 4); v += __shfl_xor(v, 8);
  return v;
}
// GELU, tanh/sigmoid form: v*sigmoid(1.5957692*(v+0.044715 v^3)).
// |dev from exact erf-GELU| <= ~3e-4; after GEMM2 (w2 sigma 0.02) ~1e-4 on output.
__device__ __forceinline__ float gelu(float v){
  float v2 = v * v;
  float inner = fmaf(v2, -0.07135806f, -1.5957692f);   // -1.5958*(1+0.044715 v^2)
  float e = __expf(v * inner);
  return v * __builtin_amdgcn_rcpf(1.0f + e);
}

// ---- LDS fragment helpers: bf16 tiles, XOR-swizzled (col ^ ((row&7)<<3)) ----
template<int STRIDE>
__device__ __forceinline__ bf16x8 ldfrag(const u16* m, int rowbase, int colbase, int lane){
  int row = rowbase + (lane & 15);
  int col = colbase + ((lane >> 4) << 3);
  return *(const bf16x8*)&m[row * STRIDE + (col ^ ((row & 7) << 3))];
}
template<int STRIDE>
__device__ __forceinline__ void stfrag(u16* m, int rowbase, int colbase, f32x4 v, float s, int lane){
  int col = colbase + (lane & 15);
  int r0  = rowbase + ((lane >> 4) << 2);
  #pragma unroll
  for (int r = 0; r < 4; ++r){
    int row = r0 + r;
    m[row * STRIDE + (col ^ ((row & 7) << 3))] = f2b(v[r] * s);
  }
}
// store transposed: element (row,col) -> m[col][row]
__device__ __forceinline__ void stfragT(u16* m, int rowbase, int colbase, f32x4 v, int lane){
  int col = colbase + (lane & 15);
  int r0  = rowbase + ((lane >> 4) << 2);
  #pragma unroll
  for (int r = 0; r < 4; ++r){
    int row = r0 + r;
    m[col * 64 + (row ^ ((col & 7) << 3))] = f2b(v[r]);
  }
}

// ---------------- prep: weights -> bf16 B-fragment order in d_ws ----------------
// wfq: [mat3][head4][kk2][ct4][lane64][8]   49152 u16
// wfo: [kk8][ct4][lane64][8]                16384 u16
// wf1: [kk2][nt16][lane64][8]               16384 u16
// wf2: [kk8][nt4][lane64][8]                16384 u16
__global__ __launch_bounds__(256) void k_prep(
    const float* __restrict__ wq, const float* __restrict__ wk,
    const float* __restrict__ wv, const float* __restrict__ wo,
    const float* __restrict__ w1, const float* __restrict__ w2,
    u16* __restrict__ wfq){
  int idx = blockIdx.x * 256 + threadIdx.x;
  int e = idx & 7, lane = (idx >> 3) & 63;
  if (idx < 49152){
    int ct = (idx >> 9) & 3, kk = (idx >> 11) & 1, hh = (idx >> 12) & 3, m = idx >> 14;
    int c = kk * 32 + ((lane >> 4) << 3) + e;
    int d = (ct << 4) + (lane & 15);
    const float* W = (m == 0) ? wq : ((m == 1) ? wk : wv);
    wfq[idx] = f2b(W[(c * 4 + hh) * 64 + d]);
  } else if (idx < 65536){
    int j = idx - 49152;
    int ct = (j >> 9) & 3, kk = (j >> 11) & 7;
    int k = kk * 32 + ((lane >> 4) << 3) + e;
    int c = (ct << 4) + (lane & 15);
    wfq[idx] = f2b(wo[k * 64 + c]);
  } else if (idx < 81920){
    int j = idx - 65536;
    int nt = (j >> 9) & 15, kk = (j >> 13) & 1;
    int c = kk * 32 + ((lane >> 4) << 3) + e;
    int f = nt * 16 + (lane & 15);
    wfq[idx] = f2b(w1[c * 256 + f]);
  } else {
    int j = idx - 81920;
    int nt = (j >> 9) & 3, kk = (j >> 11) & 7;
    int f = kk * 32 + ((lane >> 4) << 3) + e;
    int c = nt * 16 + (lane & 15);
    wfq[idx] = f2b(w2[f * 64 + c]);
  }
}

// ------- fused LN1 + window MHA + out-proj + x2 + LN2 + FFN (all MFMA) -------
// one block (4 waves) per window; wave owns 16 token rows. 32KB LDS.
__global__ __launch_bounds__(256, 4) void k_mega(
    const float* __restrict__ x,
    const float* __restrict__ ln1g, const float* __restrict__ ln1b,
    const float* __restrict__ bq, const float* __restrict__ bk,
    const float* __restrict__ bv, const float* __restrict__ bo,
    const float* __restrict__ ln2g, const float* __restrict__ ln2b,
    const float* __restrict__ b1, const float* __restrict__ b2,
    const u16* __restrict__ wf,
    float* __restrict__ out){
  __shared__ alignas(16) u16 sh[16384];   // 32KB: 4 x [64][64] bf16 buffers
  u16* hs = sh;           // LN1(x) (own-wave rows only); later LN2 result; later y1 cb0
  u16* qs = sh + 4096;    // Q -> P -> O_h (wave-private rows); later y1 cb1
  u16* ks = sh + 8192;    // K (cross-wave); later y1 cb2
  u16* vt = sh + 12288;   // V^T (cross-wave); later y1 cb3
  const u16* wfq = wf;
  const u16* wfo = wf + 49152;
  const u16* wf1 = wf + 65536;
  const u16* wf2 = wf + 81920;

  int tid = threadIdx.x, wg = tid >> 6, lane = tid & 63;
  int win = blockIdx.x;
  int d0 = (win >> 8) << 2, h0 = ((win >> 4) & 15) << 2, w0 = (win & 15) << 2;
  int tb = wg * 16;
  int c0 = lane & 15, g4 = (lane >> 4) << 2;

  // ---- LN1, vectorized: lane holds 4 channels of one row; 4 rows/iter. ----
  {
    int c4 = c0 * 4;
    int sub = lane >> 4;
    const float4 g4v = *(const float4*)&ln1g[c4];
    const float4 b4v = *(const float4*)&ln1b[c4];
    #pragma unroll
    for (int i = 0; i < 4; ++i){
      int l = tb + i * 4 + sub;
      int gd = d0 + (l >> 4), gh = h0 + ((l >> 2) & 3), gw = w0 + (l & 3);
      const float4 xv = *(const float4*)&x[(((gd * 64 + gh) * 64 + gw) << 6) + c4];
      float s = grp16_sum(xv.x + xv.y + xv.z + xv.w);
      float mn = s * 0.015625f;
      float e0 = xv.x - mn, e1 = xv.y - mn, e2 = xv.z - mn, e3 = xv.w - mn;
      float q = grp16_sum(e0*e0 + e1*e1 + e2*e2 + e3*e3);
      float rs = rsqrtf(q * 0.015625f + 1e-5f);
      float n0 = e0 * rs * g4v.x + b4v.x;
      float n1 = e1 * rs * g4v.y + b4v.y;
      float n2 = e2 * rs * g4v.z + b4v.z;
      float n3 = e3 * rs * g4v.w + b4v.w;
      // c4 is 4-aligned; XOR swizzle only touches bits >=3 -> 8B-aligned uint2 store
      *(uint2*)&hs[l * 64 + (c4 ^ ((l & 7) << 3))] = (uint2){pack2(n0, n1), pack2(n2, n3)};
    }
  }

  // ---- hoisted QKV A-fragments: identical across Q/K/V and all heads ----
  bf16x8 xa0 = ldfrag<64>(hs, tb, 0, lane);    // own rows; in-wave DS ordering
  bf16x8 xa1 = ldfrag<64>(hs, tb, 32, lane);

  f32x4 oacc[4];
  #pragma unroll
  for (int ct = 0; ct < 4; ++ct){
    float b0 = bo[ct * 16 + c0];
    oacc[ct] = (f32x4){b0, b0, b0, b0};
  }

  for (int hh = 0; hh < 4; ++hh){
    // ---- QKV projection: three sequential passes (low reg pressure) ----
    #pragma unroll
    for (int m = 0; m < 3; ++m){
      const float* bias = (m == 0) ? bq : ((m == 1) ? bk : bv);
      f32x4 acc[4];
      #pragma unroll
      for (int ct = 0; ct < 4; ++ct){
        float bb = bias[hh * 64 + ct * 16 + c0];
        acc[ct] = (f32x4){bb, bb, bb, bb};
      }
      #pragma unroll
      for (int kk = 0; kk < 2; ++kk){
        bf16x8 a = (kk == 0) ? xa0 : xa1;
        const u16* base = wfq + m * 16384 + ((hh * 2 + kk) * 4) * 512 + lane * 8;
        #pragma unroll
        for (int ct = 0; ct < 4; ++ct)
          acc[ct] = __builtin_amdgcn_mfma_f32_16x16x32_bf16(
              a, *(const bf16x8*)(base + ct * 512), acc[ct], 0, 0, 0);
      }
      if (m == 0){
        #pragma unroll
        for (int ct = 0; ct < 4; ++ct) stfrag<64>(qs, tb, ct * 16, acc[ct], 0.125f, lane);
      } else if (m == 1){
        #pragma unroll
        for (int ct = 0; ct < 4; ++ct) stfrag<64>(ks, tb, ct * 16, acc[ct], 1.0f, lane);
      } else {
        #pragma unroll
        for (int ct = 0; ct < 4; ++ct) stfragT(vt, tb, ct * 16, acc[ct], lane);
      }
    }
    __syncthreads();   // ks/vt read cross-wave

    // ---- att = Q K^T  (Q fully consumed from qs before P overwrites it) ----
    f32x4 att[4];
    #pragma unroll
    for (int ct = 0; ct < 4; ++ct) att[ct] = (f32x4){0.f, 0.f, 0.f, 0.f};
    #pragma unroll
    for (int kk = 0; kk < 2; ++kk){
      bf16x8 a = ldfrag<64>(qs, tb, kk * 32, lane);
      #pragma unroll
      for (int ct = 0; ct < 4; ++ct)
        att[ct] = __builtin_amdgcn_mfma_f32_16x16x32_bf16(
            a, ldfrag<64>(ks, ct * 16, kk * 32, lane), att[ct], 0, 0, 0);
    }

    // ---- in-register softmax over m ----
    #pragma unroll
    for (int r = 0; r < 4; ++r){
      float m0 = fmaxf(fmaxf(att[0][r], att[1][r]), fmaxf(att[2][r], att[3][r]));
      m0 = fmaxf(m0, __shfl_xor(m0, 1));
      m0 = fmaxf(m0, __shfl_xor(m0, 2));
      m0 = fmaxf(m0, __shfl_xor(m0, 4));
      m0 = fmaxf(m0, __shfl_xor(m0, 8));
      float e0 = __expf(att[0][r] - m0), e1 = __expf(att[1][r] - m0);
      float e2 = __expf(att[2][r] - m0), e3 = __expf(att[3][r] - m0);
      float s = grp16_sum(e0 + e1 + e2 + e3);
      float inv = 1.0f / s;
      att[0][r] = e0 * inv; att[1][r] = e1 * inv;
      att[2][r] = e2 * inv; att[3][r] = e3 * inv;
    }
    #pragma unroll
    for (int ct = 0; ct < 4; ++ct) stfrag<64>(qs, tb, ct * 16, att[ct], 1.0f, lane);  // P -> qs

    // ---- O_h = P V  (P fully consumed before O_h overwrites qs) ----
    f32x4 oh[4];
    #pragma unroll
    for (int ct = 0; ct < 4; ++ct) oh[ct] = (f32x4){0.f, 0.f, 0.f, 0.f};
    #pragma unroll
    for (int kk = 0; kk < 2; ++kk){
      bf16x8 a = ldfrag<64>(qs, tb, kk * 32, lane);
      #pragma unroll
      for (int ct = 0; ct < 4; ++ct)
        oh[ct] = __builtin_amdgcn_mfma_f32_16x16x32_bf16(
            a, ldfrag<64>(vt, ct * 16, kk * 32, lane), oh[ct], 0, 0, 0);
    }
    #pragma unroll
    for (int ct = 0; ct < 4; ++ct) stfrag<64>(qs, tb, ct * 16, oh[ct], 1.0f, lane);

    // ---- out-proj accumulate ----
    #pragma unroll
    for (int kkl = 0; kkl < 2; ++kkl){
      bf16x8 a = ldfrag<64>(qs, tb, kkl * 32, lane);
      const u16* base = wfo + ((hh * 2 + kkl) * 4) * 512 + lane * 8;
      #pragma unroll
      for (int ct = 0; ct < 4; ++ct)
        oacc[ct] = __builtin_amdgcn_mfma_f32_16x16x32_bf16(
            a, *(const bf16x8*)(base + ct * 512), oacc[ct], 0, 0, 0);
    }
    __syncthreads();   // before next head overwrites ks/vt (and before FFN LDS reuse)
  }

  // ======== fused x2 + LN2 + FFN (wave-private rows from here: no barriers) ========
  {
    float g2[4], b2l[4];
    #pragma unroll
    for (int ct = 0; ct < 4; ++ct){
      g2[ct] = ln2g[ct * 16 + c0];
      b2l[ct] = ln2b[ct * 16 + c0];
    }
    #pragma unroll
    for (int r = 0; r < 4; ++r){
      float v0 = 2.0f * oacc[0][r], v1 = 2.0f * oacc[1][r];
      float v2 = 2.0f * oacc[2][r], v3 = 2.0f * oacc[3][r];
      float s = grp16_sum(v0 + v1 + v2 + v3);
      float mn = s * 0.015625f;
      float d0f = v0 - mn, d1 = v1 - mn, d2 = v2 - mn, d3 = v3 - mn;
      float q = grp16_sum(d0f*d0f + d1*d1 + d2*d2 + d3*d3);
      float rs = rsqrtf(q * 0.015625f + 1e-5f);
      int row = tb + g4 + r;
      hs[row * 64 + ((0 * 16 + c0) ^ ((row & 7) << 3))] = f2b(d0f * rs * g2[0] + b2l[0]);
      hs[row * 64 + ((1 * 16 + c0) ^ ((row & 7) << 3))] = f2b(d1 * rs * g2[1] + b2l[1]);
      hs[row * 64 + ((2 * 16 + c0) ^ ((row & 7) << 3))] = f2b(d2 * rs * g2[2] + b2l[2]);
      hs[row * 64 + ((3 * 16 + c0) ^ ((row & 7) << 3))] = f2b(d3 * rs * g2[3] + b2l[3]);
    }
  }

  // ---- GEMM1: [16,64] x [64,256] -> y1 (GELU, bf16) ----
  // y1 col-block cb (64 cols) -> buffer cb at this wave's own rows tb..tb+15.
  {
    bf16x8 a0 = ldfrag<64>(hs, tb, 0, lane);
    bf16x8 a1 = ldfrag<64>(hs, tb, 32, lane);
    #pragma unroll
    for (int half = 0; half < 2; ++half){
      f32x4 acc1[8];
      #pragma unroll
      for (int nt = 0; nt < 8; ++nt){
        float bb = b1[(half * 8 + nt) * 16 + c0];
        acc1[nt] = (f32x4){bb, bb, bb, bb};
      }
      const u16* base0 = wf1 + half * 8 * 512 + lane * 8;
      #pragma unroll
      for (int nt = 0; nt < 8; ++nt)
        acc1[nt] = __builtin_amdgcn_mfma_f32_16x16x32_bf16(
            a0, *(const bf16x8*)(base0 + nt * 512), acc1[nt], 0, 0, 0);
      #pragma unroll
      for (int nt = 0; nt < 8; ++nt)
        acc1[nt] = __builtin_amdgcn_mfma_f32_16x16x32_bf16(
            a1, *(const bf16x8*)(base0 + 16 * 512 + nt * 512), acc1[nt], 0, 0, 0);
      #pragma unroll
      for (int nt = 0; nt < 8; ++nt){
        f32x4 v = acc1[nt];
        f32x4 y;
        #pragma unroll
        for (int r = 0; r < 4; ++r) y[r] = gelu(v[r]);
        int gnt = half * 8 + nt;                 // global col tile 0..15
        stfrag<64>(sh + (gnt >> 2) * 4096, tb, (gnt & 3) * 16, y, 1.0f, lane);
      }
    }
  }

  // ---- GEMM2: [16,256] x [256,64] -> out (fp32, merged voxel layout) ----
  {
    f32x4 acc2[4];
    #pragma unroll
    for (int nt = 0; nt < 4; ++nt){
      float bb = b2[nt * 16 + c0];
      acc2[nt] = (f32x4){bb, bb, bb, bb};
    }
    #pragma unroll
    for (int kk = 0; kk < 8; ++kk){
      bf16x8 a = ldfrag<64>(sh + (kk >> 1) * 4096, tb, (kk & 1) * 32, lane);
      const u16* base = wf2 + kk * 4 * 512 + lane * 8;
      #pragma unroll
      for (int nt = 0; nt < 4; ++nt)
        acc2[nt] = __builtin_amdgcn_mfma_f32_16x16x32_bf16(
            a, *(const bf16x8*)(base + nt * 512), acc2[nt], 0, 0, 0);
    }
    #pragma unroll
    for (int r = 0; r < 4; ++r){
      int l = tb + g4 + r;
      int gd = d0 + (l >> 4), gh = h0 + ((l >> 2) & 3), gw = w0 + (l & 3);
      float* orow = out + ((gd * 64 + gh) * 64 + gw) * 64;
      #pragma unroll
      for (int nt = 0; nt < 4; ++nt)
        orow[nt * 16 + c0] = acc2[nt][r];
    }
  }
}

extern "C" void kernel_launch(void* const* d_in, const int* in_sizes, int n_in,
                              void* d_out, int out_size, void* d_ws, size_t ws_size,
                              hipStream_t stream){
  const float* x    = (const float*)d_in[0];
  const float* ln1g = (const float*)d_in[1];
  const float* ln1b = (const float*)d_in[2];
  const float* wq   = (const float*)d_in[3];
  const float* bq   = (const float*)d_in[4];
  const float* wk   = (const float*)d_in[5];
  const float* bk   = (const float*)d_in[6];
  const float* wv   = (const float*)d_in[7];
  const float* bv   = (const float*)d_in[8];
  const float* wo   = (const float*)d_in[9];
  const float* bo   = (const float*)d_in[10];
  const float* ln2g = (const float*)d_in[11];
  const float* ln2b = (const float*)d_in[12];
  const float* w1   = (const float*)d_in[13];
  const float* b1   = (const float*)d_in[14];
  const float* w2   = (const float*)d_in[15];
  const float* b2   = (const float*)d_in[16];

  u16* wf = (u16*)d_ws;     // 192KB of bf16 weight fragments
  float* out = (float*)d_out;

  k_prep<<<384, 256, 0, stream>>>(wq, wk, wv, wo, w1, w2, wf);
  k_mega<<<NWIN, 256, 0, stream>>>(x, ln1g, ln1b, bq, bk, bv, bo,
                                   ln2g, ln2b, b1, b2, wf, out);
}

// Round 9
// 167.152 us; speedup vs baseline: 1.2787x; 1.2787x over previous
//
#include <hip/hip_runtime.h>
#include <math.h>

#define NWIN 4096    // (64/4)^3 windows

typedef unsigned short u16;
typedef __bf16 bf16;
typedef __attribute__((ext_vector_type(8))) __bf16 bf16x8;
typedef __attribute__((ext_vector_type(4))) float f32x4;

__device__ __forceinline__ u16 f2b(float f){
  return __builtin_bit_cast(u16, (bf16)f);
}
__device__ __forceinline__ float wred_sum(float v){
  #pragma unroll
  for (int off = 32; off; off >>= 1) v += __shfl_xor(v, off);
  return v;
}
__device__ __forceinline__ float grp16_sum(float v){
  v += __shfl_xor(v, 1); v += __shfl_xor(v, 2);
  v += __shfl_xor(v, 4); v += __shfl_xor(v, 8);
  return v;
}
// GELU, sigmoid/tanh form: v*sigmoid(1.5957692*(v+0.044715 v^3)).
// |dev from exact erf-GELU| <= ~3e-4 on y1; ~1e-4 on output after GEMM2 (w2 sigma 0.02).
__device__ __forceinline__ float gelu(float v){
  float v2 = v * v;
  float inner = fmaf(v2, -0.07135806f, -1.5957692f);   // -1.5958*(1+0.044715 v^2)
  float e = __expf(v * inner);
  return v * __builtin_amdgcn_rcpf(1.0f + e);
}

// ---- LDS fragment helpers: bf16 tiles, XOR-swizzled (col ^ ((row&7)<<3)) ----
template<int STRIDE>
__device__ __forceinline__ bf16x8 ldfrag(const u16* m, int rowbase, int colbase, int lane){
  int row = rowbase + (lane & 15);
  int col = colbase + ((lane >> 4) << 3);
  return *(const bf16x8*)&m[row * STRIDE + (col ^ ((row & 7) << 3))];
}
template<int STRIDE>
__device__ __forceinline__ void stfrag(u16* m, int rowbase, int colbase, f32x4 v, float s, int lane){
  int col = colbase + (lane & 15);
  int r0  = rowbase + ((lane >> 4) << 2);
  #pragma unroll
  for (int r = 0; r < 4; ++r){
    int row = r0 + r;
    m[row * STRIDE + (col ^ ((row & 7) << 3))] = f2b(v[r] * s);
  }
}
// store transposed: element (row,col) -> m[col][row]
__device__ __forceinline__ void stfragT(u16* m, int rowbase, int colbase, f32x4 v, int lane){
  int col = colbase + (lane & 15);
  int r0  = rowbase + ((lane >> 4) << 2);
  #pragma unroll
  for (int r = 0; r < 4; ++r){
    int row = r0 + r;
    m[col * 64 + (row ^ ((col & 7) << 3))] = f2b(v[r]);
  }
}

// ---------------- prep: weights -> bf16 B-fragment order in d_ws ----------------
// wfq: [mat3][head4][kk2][ct4][lane64][8]   49152 u16
// wfo: [kk8][ct4][lane64][8]                16384 u16
// wf1: [kk2][nt16][lane64][8]               16384 u16
// wf2: [kk8][nt4][lane64][8]                16384 u16
__global__ __launch_bounds__(256) void k_prep(
    const float* __restrict__ wq, const float* __restrict__ wk,
    const float* __restrict__ wv, const float* __restrict__ wo,
    const float* __restrict__ w1, const float* __restrict__ w2,
    u16* __restrict__ wfq){
  int idx = blockIdx.x * 256 + threadIdx.x;
  int e = idx & 7, lane = (idx >> 3) & 63;
  if (idx < 49152){
    int ct = (idx >> 9) & 3, kk = (idx >> 11) & 1, hh = (idx >> 12) & 3, m = idx >> 14;
    int c = kk * 32 + ((lane >> 4) << 3) + e;
    int d = (ct << 4) + (lane & 15);
    const float* W = (m == 0) ? wq : ((m == 1) ? wk : wv);
    wfq[idx] = f2b(W[(c * 4 + hh) * 64 + d]);
  } else if (idx < 65536){
    int j = idx - 49152;
    int ct = (j >> 9) & 3, kk = (j >> 11) & 7;
    int k = kk * 32 + ((lane >> 4) << 3) + e;
    int c = (ct << 4) + (lane & 15);
    wfq[idx] = f2b(wo[k * 64 + c]);
  } else if (idx < 81920){
    int j = idx - 65536;
    int nt = (j >> 9) & 15, kk = (j >> 13) & 1;
    int c = kk * 32 + ((lane >> 4) << 3) + e;
    int f = nt * 16 + (lane & 15);
    wfq[idx] = f2b(w1[c * 256 + f]);
  } else {
    int j = idx - 81920;
    int nt = (j >> 9) & 3, kk = (j >> 11) & 7;
    int f = kk * 32 + ((lane >> 4) << 3) + e;
    int c = nt * 16 + (lane & 15);
    wfq[idx] = f2b(w2[f * 64 + c]);
  }
}

// ------- fused LN1 + window MHA + out-proj + x2 + LN2 + FFN (all MFMA) -------
// one block (4 waves) per window; wave owns 16 token rows. 32KB LDS.
// launch_bounds(256,4): VGPR budget 128 (compiles ~64, NO spill — (256,5) spilled).
__global__ __launch_bounds__(256, 4) void k_mega(
    const float* __restrict__ x,
    const float* __restrict__ ln1g, const float* __restrict__ ln1b,
    const float* __restrict__ bq, const float* __restrict__ bk,
    const float* __restrict__ bv, const float* __restrict__ bo,
    const float* __restrict__ ln2g, const float* __restrict__ ln2b,
    const float* __restrict__ b1, const float* __restrict__ b2,
    const u16* __restrict__ wf,
    float* __restrict__ out){
  __shared__ alignas(16) u16 sh[16384];   // 32KB: 4 x [64][64] bf16 buffers
  u16* hs = sh;           // LN1(x); later LN2 result; later y1 col-block 0 (per-wave rows)
  u16* qs = sh + 4096;    // Q -> P -> O_h (all wave-private rows); later y1 cb1
  u16* ks = sh + 8192;    // K (cross-wave); later y1 cb2
  u16* vt = sh + 12288;   // V^T (cross-wave); later y1 cb3
  const u16* wfq = wf;
  const u16* wfo = wf + 49152;
  const u16* wf1 = wf + 65536;
  const u16* wf2 = wf + 81920;

  int tid = threadIdx.x, wg = tid >> 6, lane = tid & 63;
  int win = blockIdx.x;
  int d0 = (win >> 8) << 2, h0 = ((win >> 4) & 15) << 2, w0 = (win & 15) << 2;
  int tb = wg * 16;
  int c0 = lane & 15, g4 = (lane >> 4) << 2;

  // ---- load own rows + LN1 -> hs (bf16, swizzled). Own rows: no barrier. ----
  {
    float gv = ln1g[lane], bb = ln1b[lane];
    #pragma unroll
    for (int j = 0; j < 16; ++j){
      int l = tb + j;
      int gd = d0 + (l >> 4), gh = h0 + ((l >> 2) & 3), gw = w0 + (l & 3);
      float v = x[((gd * 64 + gh) * 64 + gw) * 64 + lane];
      float mn = wred_sum(v) * 0.015625f;
      float dv = v - mn;
      float var = wred_sum(dv * dv) * 0.015625f;
      float n = dv * rsqrtf(var + 1e-5f) * gv + bb;
      hs[l * 64 + (lane ^ ((l & 7) << 3))] = f2b(n);
    }
  }

  f32x4 oacc[4];
  #pragma unroll
  for (int ct = 0; ct < 4; ++ct){
    float b0 = bo[ct * 16 + c0];
    oacc[ct] = (f32x4){b0, b0, b0, b0};
  }

  for (int hh = 0; hh < 4; ++hh){
    // ---- QKV projection: three sequential passes (low reg pressure) ----
    #pragma unroll
    for (int m = 0; m < 3; ++m){
      const float* bias = (m == 0) ? bq : ((m == 1) ? bk : bv);
      f32x4 acc[4];
      #pragma unroll
      for (int ct = 0; ct < 4; ++ct){
        float bb = bias[hh * 64 + ct * 16 + c0];
        acc[ct] = (f32x4){bb, bb, bb, bb};
      }
      #pragma unroll
      for (int kk = 0; kk < 2; ++kk){
        bf16x8 a = ldfrag<64>(hs, tb, kk * 32, lane);
        const u16* base = wfq + m * 16384 + ((hh * 2 + kk) * 4) * 512 + lane * 8;
        #pragma unroll
        for (int ct = 0; ct < 4; ++ct)
          acc[ct] = __builtin_amdgcn_mfma_f32_16x16x32_bf16(
              a, *(const bf16x8*)(base + ct * 512), acc[ct], 0, 0, 0);
      }
      if (m == 0){
        #pragma unroll
        for (int ct = 0; ct < 4; ++ct) stfrag<64>(qs, tb, ct * 16, acc[ct], 0.125f, lane);
      } else if (m == 1){
        #pragma unroll
        for (int ct = 0; ct < 4; ++ct) stfrag<64>(ks, tb, ct * 16, acc[ct], 1.0f, lane);
      } else {
        #pragma unroll
        for (int ct = 0; ct < 4; ++ct) stfragT(vt, tb, ct * 16, acc[ct], lane);
      }
    }
    __syncthreads();   // ks/vt read cross-wave

    // ---- att = Q K^T  (Q fully consumed from qs before P overwrites it) ----
    f32x4 att[4];
    #pragma unroll
    for (int ct = 0; ct < 4; ++ct) att[ct] = (f32x4){0.f, 0.f, 0.f, 0.f};
    #pragma unroll
    for (int kk = 0; kk < 2; ++kk){
      bf16x8 a = ldfrag<64>(qs, tb, kk * 32, lane);
      #pragma unroll
      for (int ct = 0; ct < 4; ++ct)
        att[ct] = __builtin_amdgcn_mfma_f32_16x16x32_bf16(
            a, ldfrag<64>(ks, ct * 16, kk * 32, lane), att[ct], 0, 0, 0);
    }

    // ---- in-register softmax over m ----
    #pragma unroll
    for (int r = 0; r < 4; ++r){
      float m0 = fmaxf(fmaxf(att[0][r], att[1][r]), fmaxf(att[2][r], att[3][r]));
      m0 = fmaxf(m0, __shfl_xor(m0, 1));
      m0 = fmaxf(m0, __shfl_xor(m0, 2));
      m0 = fmaxf(m0, __shfl_xor(m0, 4));
      m0 = fmaxf(m0, __shfl_xor(m0, 8));
      float e0 = __expf(att[0][r] - m0), e1 = __expf(att[1][r] - m0);
      float e2 = __expf(att[2][r] - m0), e3 = __expf(att[3][r] - m0);
      float s = grp16_sum(e0 + e1 + e2 + e3);
      float inv = 1.0f / s;
      att[0][r] = e0 * inv; att[1][r] = e1 * inv;
      att[2][r] = e2 * inv; att[3][r] = e3 * inv;
    }
    #pragma unroll
    for (int ct = 0; ct < 4; ++ct) stfrag<64>(qs, tb, ct * 16, att[ct], 1.0f, lane);  // P -> qs

    // ---- O_h = P V  (P fully consumed before O_h overwrites qs) ----
    f32x4 oh[4];
    #pragma unroll
    for (int ct = 0; ct < 4; ++ct) oh[ct] = (f32x4){0.f, 0.f, 0.f, 0.f};
    #pragma unroll
    for (int kk = 0; kk < 2; ++kk){
      bf16x8 a = ldfrag<64>(qs, tb, kk * 32, lane);
      #pragma unroll
      for (int ct = 0; ct < 4; ++ct)
        oh[ct] = __builtin_amdgcn_mfma_f32_16x16x32_bf16(
            a, ldfrag<64>(vt, ct * 16, kk * 32, lane), oh[ct], 0, 0, 0);
    }
    #pragma unroll
    for (int ct = 0; ct < 4; ++ct) stfrag<64>(qs, tb, ct * 16, oh[ct], 1.0f, lane);

    // ---- out-proj accumulate ----
    #pragma unroll
    for (int kkl = 0; kkl < 2; ++kkl){
      bf16x8 a = ldfrag<64>(qs, tb, kkl * 32, lane);
      const u16* base = wfo + ((hh * 2 + kkl) * 4) * 512 + lane * 8;
      #pragma unroll
      for (int ct = 0; ct < 4; ++ct)
        oacc[ct] = __builtin_amdgcn_mfma_f32_16x16x32_bf16(
            a, *(const bf16x8*)(base + ct * 512), oacc[ct], 0, 0, 0);
    }
    __syncthreads();   // before next head overwrites ks/vt (and before FFN LDS reuse)
  }

  // ======== fused x2 + LN2 + FFN (wave-private rows from here: no barriers) ========
  {
    float g2[4], b2l[4];
    #pragma unroll
    for (int ct = 0; ct < 4; ++ct){
      g2[ct] = ln2g[ct * 16 + c0];
      b2l[ct] = ln2b[ct * 16 + c0];
    }
    #pragma unroll
    for (int r = 0; r < 4; ++r){
      float v0 = 2.0f * oacc[0][r], v1 = 2.0f * oacc[1][r];
      float v2 = 2.0f * oacc[2][r], v3 = 2.0f * oacc[3][r];
      float s = grp16_sum(v0 + v1 + v2 + v3);
      float mn = s * 0.015625f;
      float d0f = v0 - mn, d1 = v1 - mn, d2 = v2 - mn, d3 = v3 - mn;
      float q = grp16_sum(d0f*d0f + d1*d1 + d2*d2 + d3*d3);
      float rs = rsqrtf(q * 0.015625f + 1e-5f);
      int row = tb + g4 + r;
      hs[row * 64 + ((0 * 16 + c0) ^ ((row & 7) << 3))] = f2b(d0f * rs * g2[0] + b2l[0]);
      hs[row * 64 + ((1 * 16 + c0) ^ ((row & 7) << 3))] = f2b(d1 * rs * g2[1] + b2l[1]);
      hs[row * 64 + ((2 * 16 + c0) ^ ((row & 7) << 3))] = f2b(d2 * rs * g2[2] + b2l[2]);
      hs[row * 64 + ((3 * 16 + c0) ^ ((row & 7) << 3))] = f2b(d3 * rs * g2[3] + b2l[3]);
    }
  }

  // ---- GEMM1: [16,64] x [64,256] -> y1 (GELU, bf16) ----
  // y1 col-block cb (64 cols) lives in buffer cb at this wave's own rows tb..tb+15.
  // Preload both hs A-fragments BEFORE y1 overwrites the hs slice.
  {
    bf16x8 a0 = ldfrag<64>(hs, tb, 0, lane);
    bf16x8 a1 = ldfrag<64>(hs, tb, 32, lane);
    #pragma unroll
    for (int half = 0; half < 2; ++half){
      f32x4 acc1[8];
      #pragma unroll
      for (int nt = 0; nt < 8; ++nt){
        float bb = b1[(half * 8 + nt) * 16 + c0];
        acc1[nt] = (f32x4){bb, bb, bb, bb};
      }
      const u16* base0 = wf1 + half * 8 * 512 + lane * 8;
      #pragma unroll
      for (int nt = 0; nt < 8; ++nt)
        acc1[nt] = __builtin_amdgcn_mfma_f32_16x16x32_bf16(
            a0, *(const bf16x8*)(base0 + nt * 512), acc1[nt], 0, 0, 0);
      #pragma unroll
      for (int nt = 0; nt < 8; ++nt)
        acc1[nt] = __builtin_amdgcn_mfma_f32_16x16x32_bf16(
            a1, *(const bf16x8*)(base0 + 16 * 512 + nt * 512), acc1[nt], 0, 0, 0);
      #pragma unroll
      for (int nt = 0; nt < 8; ++nt){
        f32x4 v = acc1[nt];
        f32x4 y;
        #pragma unroll
        for (int r = 0; r < 4; ++r) y[r] = gelu(v[r]);
        int gnt = half * 8 + nt;                 // global col tile 0..15
        stfrag<64>(sh + (gnt >> 2) * 4096, tb, (gnt & 3) * 16, y, 1.0f, lane);
      }
    }
  }

  // ---- GEMM2: [16,256] x [256,64] -> out (fp32, merged voxel layout) ----
  {
    f32x4 acc2[4];
    #pragma unroll
    for (int nt = 0; nt < 4; ++nt){
      float bb = b2[nt * 16 + c0];
      acc2[nt] = (f32x4){bb, bb, bb, bb};
    }
    #pragma unroll
    for (int kk = 0; kk < 8; ++kk){
      bf16x8 a = ldfrag<64>(sh + (kk >> 1) * 4096, tb, (kk & 1) * 32, lane);
      const u16* base = wf2 + kk * 4 * 512 + lane * 8;
      #pragma unroll
      for (int nt = 0; nt < 4; ++nt)
        acc2[nt] = __builtin_amdgcn_mfma_f32_16x16x32_bf16(
            a, *(const bf16x8*)(base + nt * 512), acc2[nt], 0, 0, 0);
    }
    #pragma unroll
    for (int r = 0; r < 4; ++r){
      int l = tb + g4 + r;
      int gd = d0 + (l >> 4), gh = h0 + ((l >> 2) & 3), gw = w0 + (l & 3);
      float* orow = out + ((gd * 64 + gh) * 64 + gw) * 64;
      #pragma unroll
      for (int nt = 0; nt < 4; ++nt)
        orow[nt * 16 + c0] = acc2[nt][r];
    }
  }
}

extern "C" void kernel_launch(void* const* d_in, const int* in_sizes, int n_in,
                              void* d_out, int out_size, void* d_ws, size_t ws_size,
                              hipStream_t stream){
  const float* x    = (const float*)d_in[0];
  const float* ln1g = (const float*)d_in[1];
  const float* ln1b = (const float*)d_in[2];
  const float* wq   = (const float*)d_in[3];
  const float* bq   = (const float*)d_in[4];
  const float* wk   = (const float*)d_in[5];
  const float* bk   = (const float*)d_in[6];
  const float* wv   = (const float*)d_in[7];
  const float* bv   = (const float*)d_in[8];
  const float* wo   = (const float*)d_in[9];
  const float* bo   = (const float*)d_in[10];
  const float* ln2g = (const float*)d_in[11];
  const float* ln2b = (const float*)d_in[12];
  const float* w1   = (const float*)d_in[13];
  const float* b1   = (const float*)d_in[14];
  const float* w2   = (const float*)d_in[15];
  const float* b2   = (const float*)d_in[16];

  u16* wf = (u16*)d_ws;     // 192KB of bf16 weight fragments
  float* out = (float*)d_out;

  k_prep<<<384, 256, 0, stream>>>(wq, wk, wv, wo, w1, w2, wf);
  k_mega<<<NWIN, 256, 0, stream>>>(x, ln1g, ln1b, bq, bk, bv, bo,
                                   ln2g, ln2b, b1, b2, wf, out);
}